// Round 8
// baseline (579.284 us; speedup 1.0000x reference)
//
#include <hip/hip_runtime.h>
#include <hip/hip_bf16.h>
#include <stdint.h>

#define NN 50000
#define NE 800000
#define EPS 1e-5f

// CSR bucket params
#define KB 196       // buckets = ceil(NN / NPB)
#define SH 8         // bucket = dst >> SH
#define NPB 256      // nodes per bucket
#define RCAP 4500    // slots per bucket (mean 4082, +6.6 sigma)
#define PT2 2048     // edges per DS-partition block
#define NT2 391      // tiles per layer = ceil(NE/PT2)

typedef __attribute__((ext_vector_type(8))) short bf16x8;
typedef __attribute__((ext_vector_type(4))) float floatx4;

static __device__ __forceinline__ float bf2f(unsigned int u){
  union { unsigned int i; float f; } c; c.i = u << 16; return c.f;
}
static __device__ __forceinline__ unsigned short f2bf(float f){
  union { float f; unsigned int i; } c; c.f = f;
  unsigned int x = c.i;
  return (unsigned short)((x + 0x7fffu + ((x >> 16) & 1u)) >> 16);
}

// fused f32 -> bf16 converter for x + the 6 GEMM weight matrices; also zeros bucket cursors
#define CVT_X   3200000
#define CVT_W1  3212288
#define CVT_WL2 3228672
#define CVT_WR2 3245056
#define CVT_WL3 3261440
#define CVT_WR3 3277824
#define CVT_END 3290112
__global__ void k_cvt_all(const float* __restrict__ x,  const float* __restrict__ W1,
                          const float* __restrict__ Wl2, const float* __restrict__ Wr2,
                          const float* __restrict__ Wl3, const float* __restrict__ Wr3,
                          const float* __restrict__ W4,
                          unsigned short* __restrict__ xb,  unsigned short* __restrict__ W1b,
                          unsigned short* __restrict__ Wl2b, unsigned short* __restrict__ Wr2b,
                          unsigned short* __restrict__ Wl3b, unsigned short* __restrict__ Wr3b,
                          unsigned short* __restrict__ W4b, int* __restrict__ gcur){
  int i = blockIdx.x * 256 + threadIdx.x;
  if(i >= CVT_END) return;
  if(i < 3 * KB) gcur[i] = 0;
  if(i < CVT_X)        xb[i] = f2bf(x[i]);
  else if(i < CVT_W1)  W1b[i - CVT_X]    = f2bf(W1[i - CVT_X]);
  else if(i < CVT_WL2) Wl2b[i - CVT_W1]  = f2bf(Wl2[i - CVT_W1]);
  else if(i < CVT_WR2) Wr2b[i - CVT_WL2] = f2bf(Wr2[i - CVT_WL2]);
  else if(i < CVT_WL3) Wl3b[i - CVT_WR2] = f2bf(Wl3[i - CVT_WR2]);
  else if(i < CVT_WR3) Wr3b[i - CVT_WL3] = f2bf(Wr3[i - CVT_WL3]);
  else                 W4b[i - CVT_WR3]  = f2bf(W4[i - CVT_WR3]);
}

// ---- FUSED 3-layer partition, v2: rec is EID-ONLY (dst/src recoverable via ei[eid]
// in build3) — halves flush writes, drops all src loads, LDS 28.5->20KB.
// Layer-0 blocks additionally stream-convert their ea tile to bf16 (eab) fully
// coalesced, so k_aggXE can gather 64B bf16 rows instead of 128B f32 rows. ----
__global__ void k_part3(const int* __restrict__ ei0, const int* __restrict__ ei1,
                        const int* __restrict__ ei2, int* __restrict__ gcur,
                        int* __restrict__ rec,
                        const float* __restrict__ ea, unsigned int* __restrict__ eab){
  __shared__ int2 stage[PT2];
  __shared__ int hist[KB], ex[KB], cur[KB], gbase[KB];
  __shared__ int part[256];
  __shared__ int tot;
  int layer = blockIdx.x % 3;
  int tile = (blockIdx.x / 3) * PT2;
  const int* ei = (layer == 0) ? ei0 : ((layer == 1) ? ei1 : ei2);
  int* recL = rec + (size_t)layer * KB * RCAP;
  int* gcurL = gcur + layer * KB;
  int tid = threadIdx.x;
  int cnt_local = NE - tile; if(cnt_local > PT2) cnt_local = PT2;
  for(int i = tid; i < KB; i += 256) hist[i] = 0;
  __syncthreads();
  int dst[8];
  #pragma unroll
  for(int j = 0; j < 8; j++){
    int e = tile + j * 256 + tid;
    if(e < NE){ dst[j] = ei[NE + e]; atomicAdd(&hist[dst[j] >> SH], 1); }
    else dst[j] = -1;
  }
  __syncthreads();
  int c0 = (tid < KB) ? hist[tid] : 0;
  part[tid] = c0;
  __syncthreads();
  for(int d = 1; d < 256; d <<= 1){
    int v = (tid >= d) ? part[tid - d] : 0;
    __syncthreads();
    part[tid] += v;
    __syncthreads();
  }
  if(tid < KB){
    int e = part[tid] - c0;
    ex[tid] = e; cur[tid] = e;
    gbase[tid] = atomicAdd(&gcurL[tid], c0);
  }
  if(tid == 255) tot = part[255];
  __syncthreads();
  #pragma unroll
  for(int j = 0; j < 8; j++){
    if(dst[j] >= 0){
      int b = dst[j] >> SH;
      int s = atomicAdd(&cur[b], 1);
      stage[s] = make_int2(dst[j], tile + j * 256 + tid);
    }
  }
  __syncthreads();
  for(int s = tid; s < tot; s += 256){
    int2 r = stage[s];
    int b = r.x >> SH;
    recL[b * RCAP + gbase[b] + (s - ex[b])] = r.y;
  }
  // layer-0 blocks: stream-convert this tile's ea rows to bf16 (coalesced both sides)
  if(layer == 0){
    int g = tid >> 4, li = tid & 15;
    for(int t = g; t < cnt_local; t += 16){
      size_t e = (size_t)(tile + t);
      float2 v = *(const float2*)(ea + e * 32 + li * 2);
      eab[e * 16 + li] = (unsigned int)f2bf(v.x) | ((unsigned int)f2bf(v.y) << 16);
    }
  }
}

// ---- FUSED 3-layer per-bucket CSR build, v2: rec holds eids; dst/src gathered
// from ei (ascending-ish eids -> L2-friendly). L0 -> adj2 {src,eid}; L1/L2 -> int adj. ----
__global__ void k_build3(const int* __restrict__ rec, const int* __restrict__ gcnt,
                         const int* __restrict__ ei0, const int* __restrict__ ei1,
                         const int* __restrict__ ei2,
                         int2* __restrict__ adj2, int* __restrict__ adjI1, int* __restrict__ adjI2,
                         int* __restrict__ rowbeg3, int* __restrict__ deg3){
  __shared__ int cnt[NPB], cur2[NPB];
  __shared__ int part[256];
  int layer = blockIdx.x % 3;
  int b = blockIdx.x / 3;
  int tid = threadIdx.x;
  int n0 = b << SH;
  int nr = gcnt[layer * KB + b];
  const int* ei = (layer == 0) ? ei0 : ((layer == 1) ? ei1 : ei2);
  const int* r = rec + ((size_t)layer * KB + b) * RCAP;
  cnt[tid] = 0;
  __syncthreads();
  for(int k = tid; k < nr; k += 256){
    int dst = ei[NE + r[k]];
    atomicAdd(&cnt[dst - n0], 1);
  }
  __syncthreads();
  int c0 = cnt[tid];
  part[tid] = c0;
  __syncthreads();
  for(int d = 1; d < 256; d <<= 1){
    int v = (tid >= d) ? part[tid - d] : 0;
    __syncthreads();
    part[tid] += v;
    __syncthreads();
  }
  int base = part[tid] - c0;
  cur2[tid] = base;
  __syncthreads();
  int n = n0 + tid;
  if(n < NN){ rowbeg3[layer * NN + n] = b * RCAP + base; deg3[layer * NN + n] = c0; }
  for(int k = tid; k < nr; k += 256){
    int eid = r[k];
    int dst = ei[NE + eid];
    int src = ei[eid];
    int p = atomicAdd(&cur2[dst - n0], 1);
    if(layer == 0)      adj2[b * RCAP + p]  = make_int2(src, eid);
    else if(layer == 1) adjI1[b * RCAP + p] = src;
    else                adjI2[b * RCAP + p] = src;
  }
}

// ---- fused L0 aggregation: wave per node; 16 lanes/edge, 8 edges/iter.
// lanes 0-7 gather xb row (16B each), lanes 8-15 gather eab bf16 row (8B each =
// full 64B row — HALF the random HBM bytes of the f32 version). ----
__global__ void k_aggXE(const int* __restrict__ rowbeg, const int* __restrict__ deg,
                        const int2* __restrict__ adj2,
                        const unsigned short* __restrict__ xb, const unsigned int* __restrict__ eab,
                        unsigned short* __restrict__ agg){
  int w = (blockIdx.x * blockDim.x + threadIdx.x) >> 6;
  int lane = threadIdx.x & 63;
  if(w >= NN) return;
  int sub = lane >> 4, li = lane & 15;
  int r0 = rowbeg[w], dg = deg[w], r1 = r0 + dg;
  float acc[8] = {0.f,0.f,0.f,0.f,0.f,0.f,0.f,0.f};
  for(int k = r0; k < r1; k += 8){
    int e0 = k + sub, e1 = k + 4 + sub;
    int i0 = e0 < r1 ? e0 : r1 - 1;
    int i1 = e1 < r1 ? e1 : r1 - 1;
    float m0 = e0 < r1 ? 1.f : 0.f;
    float m1 = e1 < r1 ? 1.f : 0.f;
    int2 a0 = adj2[i0], a1 = adj2[i1];
    if(li < 8){
      uint4 v0 = *(const uint4*)(xb + (size_t)a0.x * 64 + li * 8);
      uint4 v1 = *(const uint4*)(xb + (size_t)a1.x * 64 + li * 8);
      acc[0] += m0 * bf2f(v0.x & 0xffffu); acc[1] += m0 * bf2f(v0.x >> 16);
      acc[2] += m0 * bf2f(v0.y & 0xffffu); acc[3] += m0 * bf2f(v0.y >> 16);
      acc[4] += m0 * bf2f(v0.z & 0xffffu); acc[5] += m0 * bf2f(v0.z >> 16);
      acc[6] += m0 * bf2f(v0.w & 0xffffu); acc[7] += m0 * bf2f(v0.w >> 16);
      acc[0] += m1 * bf2f(v1.x & 0xffffu); acc[1] += m1 * bf2f(v1.x >> 16);
      acc[2] += m1 * bf2f(v1.y & 0xffffu); acc[3] += m1 * bf2f(v1.y >> 16);
      acc[4] += m1 * bf2f(v1.z & 0xffffu); acc[5] += m1 * bf2f(v1.z >> 16);
      acc[6] += m1 * bf2f(v1.w & 0xffffu); acc[7] += m1 * bf2f(v1.w >> 16);
    } else {
      int j = li - 8;
      uint2 p0 = *(const uint2*)(eab + (size_t)a0.y * 16 + j * 2);
      uint2 p1 = *(const uint2*)(eab + (size_t)a1.y * 16 + j * 2);
      acc[0] += m0 * bf2f(p0.x & 0xffffu); acc[1] += m0 * bf2f(p0.x >> 16);
      acc[2] += m0 * bf2f(p0.y & 0xffffu); acc[3] += m0 * bf2f(p0.y >> 16);
      acc[0] += m1 * bf2f(p1.x & 0xffffu); acc[1] += m1 * bf2f(p1.x >> 16);
      acc[2] += m1 * bf2f(p1.y & 0xffffu); acc[3] += m1 * bf2f(p1.y >> 16);
    }
  }
  #pragma unroll
  for(int d = 16; d < 64; d <<= 1){
    #pragma unroll
    for(int i = 0; i < 8; i++) acc[i] += __shfl_xor(acc[i], d, 64);
  }
  if(sub == 0){
    float inv = 1.0f / (float)(dg > 0 ? dg : 1);
    if(li < 8){
      unsigned int q0 = (unsigned int)f2bf(acc[0]*inv) | ((unsigned int)f2bf(acc[1]*inv) << 16);
      unsigned int q1 = (unsigned int)f2bf(acc[2]*inv) | ((unsigned int)f2bf(acc[3]*inv) << 16);
      unsigned int q2 = (unsigned int)f2bf(acc[4]*inv) | ((unsigned int)f2bf(acc[5]*inv) << 16);
      unsigned int q3 = (unsigned int)f2bf(acc[6]*inv) | ((unsigned int)f2bf(acc[7]*inv) << 16);
      *(uint4*)(agg + (size_t)w * 96 + li * 8) = make_uint4(q0, q1, q2, q3);
    } else {
      int j = li - 8;
      unsigned int q0 = (unsigned int)f2bf(acc[0]*inv) | ((unsigned int)f2bf(acc[1]*inv) << 16);
      unsigned int q1 = (unsigned int)f2bf(acc[2]*inv) | ((unsigned int)f2bf(acc[3]*inv) << 16);
      *(uint2*)(agg + (size_t)w * 96 + 64 + j * 4) = make_uint2(q0, q1);
    }
  }
}

// ---- h aggregation (R2-proven): wave per node; 16 lanes/edge, 8 edges/iter ----
__global__ void k_aggH(const int* __restrict__ rowbeg, const int* __restrict__ deg,
                       const int* __restrict__ adj,
                       const unsigned short* __restrict__ h, unsigned short* __restrict__ agg){
  int w = (blockIdx.x * blockDim.x + threadIdx.x) >> 6;
  int lane = threadIdx.x & 63;
  if(w >= NN) return;
  int sub = lane >> 4, li = lane & 15;
  int r0 = rowbeg[w], dg = deg[w], r1 = r0 + dg;
  float acc[8] = {0.f,0.f,0.f,0.f,0.f,0.f,0.f,0.f};
  for(int k = r0; k < r1; k += 8){
    int e0 = k + sub, e1 = k + 4 + sub;
    int i0 = e0 < r1 ? e0 : r1 - 1;
    int i1 = e1 < r1 ? e1 : r1 - 1;
    float m0 = e0 < r1 ? 1.f : 0.f;
    float m1 = e1 < r1 ? 1.f : 0.f;
    int s0 = adj[i0], s1 = adj[i1];
    uint4 v0 = *(const uint4*)(h + (size_t)s0 * 128 + li * 8);
    uint4 v1 = *(const uint4*)(h + (size_t)s1 * 128 + li * 8);
    acc[0] += m0 * bf2f(v0.x & 0xffffu); acc[1] += m0 * bf2f(v0.x >> 16);
    acc[2] += m0 * bf2f(v0.y & 0xffffu); acc[3] += m0 * bf2f(v0.y >> 16);
    acc[4] += m0 * bf2f(v0.z & 0xffffu); acc[5] += m0 * bf2f(v0.z >> 16);
    acc[6] += m0 * bf2f(v0.w & 0xffffu); acc[7] += m0 * bf2f(v0.w >> 16);
    acc[0] += m1 * bf2f(v1.x & 0xffffu); acc[1] += m1 * bf2f(v1.x >> 16);
    acc[2] += m1 * bf2f(v1.y & 0xffffu); acc[3] += m1 * bf2f(v1.y >> 16);
    acc[4] += m1 * bf2f(v1.z & 0xffffu); acc[5] += m1 * bf2f(v1.z >> 16);
    acc[6] += m1 * bf2f(v1.w & 0xffffu); acc[7] += m1 * bf2f(v1.w >> 16);
  }
  #pragma unroll
  for(int d = 16; d < 64; d <<= 1){
    #pragma unroll
    for(int i = 0; i < 8; i++) acc[i] += __shfl_xor(acc[i], d, 64);
  }
  if(sub == 0){
    float inv = 1.0f / (float)(dg > 0 ? dg : 1);
    unsigned int p0 = (unsigned int)f2bf(acc[0]*inv) | ((unsigned int)f2bf(acc[1]*inv) << 16);
    unsigned int p1 = (unsigned int)f2bf(acc[2]*inv) | ((unsigned int)f2bf(acc[3]*inv) << 16);
    unsigned int p2 = (unsigned int)f2bf(acc[4]*inv) | ((unsigned int)f2bf(acc[5]*inv) << 16);
    unsigned int p3 = (unsigned int)f2bf(acc[6]*inv) | ((unsigned int)f2bf(acc[7]*inv) << 16);
    *(uint4*)(agg + (size_t)w * 128 + li * 8) = make_uint4(p0, p1, p2, p3);
  }
}

// conv1 dense part: h1 = relu(bn(relu(mask_deg(agg @ W1^T + b1))))
__global__ void k_lin1(const unsigned short* __restrict__ agg, const unsigned short* __restrict__ W1,
                       const float* __restrict__ b1,
                       const float* __restrict__ g1, const float* __restrict__ be1,
                       const float* __restrict__ m1, const float* __restrict__ v1,
                       const int* __restrict__ deg, unsigned short* __restrict__ h1){
  int wave = (blockIdx.x * blockDim.x + threadIdx.x) >> 6;
  int lane = threadIdx.x & 63;
  int mt = wave >> 3, nt = wave & 7;
  if(mt >= 3125) return;
  int node0 = mt * 16;
  int col = lane & 15, quad = lane >> 4;
  int o = nt * 16 + col;
  int arow = node0 + col;
  floatx4 acc = {0.f, 0.f, 0.f, 0.f};
  #pragma unroll
  for(int kc = 0; kc < 3; kc++){
    bf16x8 a = *(const bf16x8*)(agg + arow * 96 + kc * 32 + quad * 8);
    bf16x8 b = *(const bf16x8*)(W1 + o * 96 + kc * 32 + quad * 8);
    acc = __builtin_amdgcn_mfma_f32_16x16x32_bf16(a, b, acc, 0, 0, 0);
  }
  float bb = b1[o];
  float sc = g1[o] * rsqrtf(v1[o] + EPS);
  float mv = m1[o], bev = be1[o];
  #pragma unroll
  for(int r = 0; r < 4; r++){
    int node = node0 + quad * 4 + r;
    float pre = (deg[node] > 0) ? (acc[r] + bb) : 0.0f;   // ref: empty segment -> mean 0, bias never added
    float t = fmaxf(pre, 0.f);
    float bn = sc * (t - mv) + bev;
    h1[node * 128 + o] = f2bf(fmaxf(bn, 0.f));
  }
}

// SAGE: hout = relu(bn(agg @ Wl^T + bl + hin @ Wr^T))
__global__ void k_sage(const unsigned short* __restrict__ agg, const unsigned short* __restrict__ hin,
                       const unsigned short* __restrict__ Wl, const float* __restrict__ bl,
                       const unsigned short* __restrict__ Wr,
                       const float* __restrict__ g, const float* __restrict__ be,
                       const float* __restrict__ m, const float* __restrict__ v,
                       unsigned short* __restrict__ hout){
  int wave = (blockIdx.x * blockDim.x + threadIdx.x) >> 6;
  int lane = threadIdx.x & 63;
  int mt = wave >> 3, nt = wave & 7;
  if(mt >= 3125) return;
  int node0 = mt * 16;
  int col = lane & 15, quad = lane >> 4;
  int o = nt * 16 + col;
  int arow = node0 + col;
  floatx4 acc = {0.f, 0.f, 0.f, 0.f};
  #pragma unroll
  for(int kc = 0; kc < 4; kc++){
    bf16x8 a = *(const bf16x8*)(agg + arow * 128 + kc * 32 + quad * 8);
    bf16x8 b = *(const bf16x8*)(Wl + o * 128 + kc * 32 + quad * 8);
    acc = __builtin_amdgcn_mfma_f32_16x16x32_bf16(a, b, acc, 0, 0, 0);
  }
  #pragma unroll
  for(int kc = 0; kc < 4; kc++){
    bf16x8 a = *(const bf16x8*)(hin + arow * 128 + kc * 32 + quad * 8);
    bf16x8 b = *(const bf16x8*)(Wr + o * 128 + kc * 32 + quad * 8);
    acc = __builtin_amdgcn_mfma_f32_16x16x32_bf16(a, b, acc, 0, 0, 0);
  }
  float blv = bl[o];
  float sc = g[o] * rsqrtf(v[o] + EPS);
  float mv = m[o], bev = be[o];
  #pragma unroll
  for(int r = 0; r < 4; r++){
    int node = node0 + quad * 4 + r;
    float pre = acc[r] + blv;
    float bn = sc * (pre - mv) + bev;
    hout[node * 128 + o] = f2bf(fmaxf(bn, 0.f));
  }
}

// readout: z = relu([h3 | x] @ W4^T + b4) (64), out = z @ W5^T + b5  (f32 out)
__global__ void k_readout(const unsigned short* __restrict__ h3, const unsigned short* __restrict__ xb,
                          const unsigned short* __restrict__ W4, const float* __restrict__ b4,
                          const float* __restrict__ W5, const float* __restrict__ b5,
                          float* __restrict__ out){
  int wave = (blockIdx.x * blockDim.x + threadIdx.x) >> 6;
  int lane = threadIdx.x & 63;
  if(wave >= 3125) return;
  int node0 = wave * 16;
  int col = lane & 15, quad = lane >> 4;
  int arow = node0 + col;
  float partial[4] = {0.f, 0.f, 0.f, 0.f};
  #pragma unroll
  for(int nt = 0; nt < 4; nt++){
    int o = nt * 16 + col;
    floatx4 acc = {0.f, 0.f, 0.f, 0.f};
    #pragma unroll
    for(int kc = 0; kc < 4; kc++){
      bf16x8 a = *(const bf16x8*)(h3 + arow * 128 + kc * 32 + quad * 8);
      bf16x8 b = *(const bf16x8*)(W4 + o * 192 + kc * 32 + quad * 8);
      acc = __builtin_amdgcn_mfma_f32_16x16x32_bf16(a, b, acc, 0, 0, 0);
    }
    #pragma unroll
    for(int kc = 0; kc < 2; kc++){
      bf16x8 a = *(const bf16x8*)(xb + arow * 64 + kc * 32 + quad * 8);
      bf16x8 b = *(const bf16x8*)(W4 + o * 192 + 128 + kc * 32 + quad * 8);
      acc = __builtin_amdgcn_mfma_f32_16x16x32_bf16(a, b, acc, 0, 0, 0);
    }
    float bb = b4[o];
    float w5 = W5[o];
    #pragma unroll
    for(int r = 0; r < 4; r++)
      partial[r] += fmaxf(acc[r] + bb, 0.f) * w5;
  }
  #pragma unroll
  for(int d = 1; d < 16; d <<= 1){
    #pragma unroll
    for(int r = 0; r < 4; r++)
      partial[r] += __shfl_xor(partial[r], d, 64);
  }
  if(col == 0){
    float b5f = b5[0];
    #pragma unroll
    for(int r = 0; r < 4; r++)
      out[node0 + quad * 4 + r] = partial[r] + b5f;
  }
}

extern "C" void kernel_launch(void* const* d_in, const int* in_sizes, int n_in,
                              void* d_out, int out_size, void* d_ws, size_t ws_size,
                              hipStream_t stream) {
  const float* x   = (const float*)d_in[0];
  const int* ei0   = (const int*)d_in[1];
  const int* ei1   = (const int*)d_in[2];
  const int* ei2   = (const int*)d_in[3];
  const float* ea  = (const float*)d_in[4];
  const float* W1  = (const float*)d_in[5];
  const float* b1  = (const float*)d_in[6];
  const float* g1  = (const float*)d_in[7];
  const float* be1 = (const float*)d_in[8];
  const float* m1  = (const float*)d_in[9];
  const float* v1  = (const float*)d_in[10];
  const float* Wl2 = (const float*)d_in[11];
  const float* bl2 = (const float*)d_in[12];
  const float* Wr2 = (const float*)d_in[13];
  const float* g2  = (const float*)d_in[14];
  const float* be2 = (const float*)d_in[15];
  const float* m2  = (const float*)d_in[16];
  const float* v2  = (const float*)d_in[17];
  const float* Wl3 = (const float*)d_in[18];
  const float* bl3 = (const float*)d_in[19];
  const float* Wr3 = (const float*)d_in[20];
  const float* g3  = (const float*)d_in[21];
  const float* be3 = (const float*)d_in[22];
  const float* m3  = (const float*)d_in[23];
  const float* v3  = (const float*)d_in[24];
  const float* W4  = (const float*)d_in[25];
  const float* b4  = (const float*)d_in[26];
  const float* W5  = (const float*)d_in[27];
  const float* b5  = (const float*)d_in[28];

  char* ws = (char*)d_ws;
  size_t off = 0;
  auto alloc = [&](size_t bytes) -> void* {
    void* p = (void*)(ws + off);
    off += (bytes + 255) & ~(size_t)255;
    return p;
  };
  int* gcur    = (int*)alloc(3 * KB * sizeof(int));
  int* rowbeg3 = (int*)alloc(3 * NN * sizeof(int));
  int* deg3    = (int*)alloc(3 * NN * sizeof(int));
  // UNION region, phase 1: eid-rec (3 layers, 10.58MB) + eab (bf16 ea, 51.2MB).
  // phase 2 (from k_lin1 onward; rec dead after build3, eab dead after aggXE):
  // h1/aggH/h2 (38.4MB). size = rec_pad + eab = 61.8MB >= 38.4MB.
  const size_t REC_PAD = (((size_t)3 * KB * RCAP * 4) + 255) & ~(size_t)255;
  char* uni    = (char*)alloc(REC_PAD + (size_t)NE * 64);
  int2* adj2   = (int2*)alloc((size_t)KB * RCAP * 8);
  int* adjI1   = (int*)alloc((size_t)KB * RCAP * 4);
  int* adjI2   = (int*)alloc((size_t)KB * RCAP * 4);
  unsigned short* agg1 = (unsigned short*)alloc((size_t)NN * 96 * 2);
  unsigned short* xb   = (unsigned short*)alloc((size_t)NN * 64 * 2);
  unsigned short* W1b  = (unsigned short*)alloc(12288 * 2);
  unsigned short* Wl2b = (unsigned short*)alloc(16384 * 2);
  unsigned short* Wr2b = (unsigned short*)alloc(16384 * 2);
  unsigned short* Wl3b = (unsigned short*)alloc(16384 * 2);
  unsigned short* Wr3b = (unsigned short*)alloc(16384 * 2);
  unsigned short* W4b  = (unsigned short*)alloc(12288 * 2);

  // phase-1 aliases inside uni
  int* recDS = (int*)uni;                                  // eid-only recs, 3 layers
  unsigned int* eab = (unsigned int*)(uni + REC_PAD);      // bf16 ea rows (64B each)
  // phase-2 aliases inside uni (h3 reuses h1's slot; ordering-safe: h written
  // only after aggXE has consumed eab)
  unsigned short* h1   = (unsigned short*)uni;
  unsigned short* aggH = h1 + (size_t)NN * 128;
  unsigned short* h2   = h1 + (size_t)2 * NN * 128;
  unsigned short* h3   = h1;

  int* rb0 = rowbeg3;            int* dg0 = deg3;
  int* rb1 = rowbeg3 + NN;       int* dg1 = deg3 + NN;
  int* rb2 = rowbeg3 + 2 * NN;   int* dg2 = deg3 + 2 * NN;

  const int gP3   = 3 * NT2;                   // 1173
  const int gB3   = 3 * KB;                    // 588
  const int gAgg  = (NN * 64) / 256;           // 12500
  const int gTile = (3125 * 8 * 64) / 256;     // 6250
  const int gRead = (3125 * 64 + 255) / 256;   // 782
  const int gCvt  = (CVT_END + 255) / 256;

  k_cvt_all<<<gCvt, 256, 0, stream>>>(x, W1, Wl2, Wr2, Wl3, Wr3, W4,
                                      xb, W1b, Wl2b, Wr2b, Wl3b, Wr3b, W4b, gcur);

  // ---- fused partition (+ ea->bf16 stream) + CSR build for all 3 layers ----
  k_part3<<<gP3, 256, 0, stream>>>(ei0, ei1, ei2, gcur, recDS, ea, eab);
  k_build3<<<gB3, 256, 0, stream>>>(recDS, gcur, ei0, ei1, ei2,
                                    adj2, adjI1, adjI2, rowbeg3, deg3);

  // ---- layer 1 (conv1) ----
  k_aggXE<<<gAgg, 256, 0, stream>>>(rb0, dg0, adj2, xb, eab, agg1);
  k_lin1<<<gTile, 256, 0, stream>>>(agg1, W1b, b1, g1, be1, m1, v1, dg0, h1);

  // ---- layer 2 (SAGE) ----
  k_aggH<<<gAgg, 256, 0, stream>>>(rb1, dg1, adjI1, h1, aggH);
  k_sage<<<gTile, 256, 0, stream>>>(aggH, h1, Wl2b, bl2, Wr2b, g2, be2, m2, v2, h2);

  // ---- layer 3 (SAGE) ----
  k_aggH<<<gAgg, 256, 0, stream>>>(rb2, dg2, adjI2, h2, aggH);
  k_sage<<<gTile, 256, 0, stream>>>(aggH, h2, Wl3b, bl3, Wr3b, g3, be3, m3, v3, h3);

  // ---- readout ----
  k_readout<<<gRead, 256, 0, stream>>>(h3, xb, W4b, b4, W5, b5, (float*)d_out);

  (void)in_sizes; (void)n_in; (void)out_size; (void)ws_size;
}

// Round 9
// 498.384 us; speedup vs baseline: 1.1623x; 1.1623x over previous
//
#include <hip/hip_runtime.h>
#include <hip/hip_bf16.h>
#include <stdint.h>

#define NN 50000
#define NE 800000
#define EPS 1e-5f

// CSR bucket params
#define KB 196       // buckets = ceil(NN / NPB)
#define SH 8         // bucket = dst >> SH
#define NPB 256      // nodes per bucket
#define RCAP 4500    // slots per bucket (mean 4082, +6.6 sigma)
#define PT2 2048     // edges per DS-partition block
#define NT2 391      // tiles per layer = ceil(NE/PT2)
#define GP3 (3 * NT2)                 // 1173 partition blocks
#define GCVT ((3290112 + 255) / 256)  // 12852 cvt blocks

typedef __attribute__((ext_vector_type(8))) short bf16x8;
typedef __attribute__((ext_vector_type(4))) float floatx4;

static __device__ __forceinline__ float bf2f(unsigned int u){
  union { unsigned int i; float f; } c; c.i = u << 16; return c.f;
}
static __device__ __forceinline__ unsigned short f2bf(float f){
  union { float f; unsigned int i; } c; c.f = f;
  unsigned int x = c.i;
  return (unsigned short)((x + 0x7fffu + ((x >> 16) & 1u)) >> 16);
}

#define CVT_X   3200000
#define CVT_W1  3212288
#define CVT_WL2 3228672
#define CVT_WR2 3245056
#define CVT_WL3 3261440
#define CVT_WR3 3277824
#define CVT_END 3290112

// ---- FUSED dispatch: blocks [0, GP3) run the 3-layer partition (layer = blk%3);
// blocks [GP3, GP3+GCVT) run the f32->bf16 converter for x + 6 weight matrices.
// The two are independent (cvt outputs first consumed 2 dispatches later); cvt's
// ~20MB stream hides under part3's barrier/scan stalls. gcur is zeroed by a
// hipMemsetAsync before this dispatch (it is read via atomicAdd here).
// Partition v3: layer-0 stages {dst, eid} (src recovered in build3 via ei0[eid]) —
// deletes the stE array (LDS 28.5->20.2 KB, 5->7 blocks/CU) and the recE buffer. ----
__global__ void k_part3cvt(const int* __restrict__ ei0, const int* __restrict__ ei1,
                           const int* __restrict__ ei2, int* __restrict__ gcur,
                           int2* __restrict__ rec,
                           const float* __restrict__ x,  const float* __restrict__ W1,
                           const float* __restrict__ Wl2, const float* __restrict__ Wr2,
                           const float* __restrict__ Wl3, const float* __restrict__ Wr3,
                           const float* __restrict__ W4,
                           unsigned short* __restrict__ xb,  unsigned short* __restrict__ W1b,
                           unsigned short* __restrict__ Wl2b, unsigned short* __restrict__ Wr2b,
                           unsigned short* __restrict__ Wl3b, unsigned short* __restrict__ Wr3b,
                           unsigned short* __restrict__ W4b){
  __shared__ int2 stage[PT2];
  __shared__ int hist[KB], ex[KB], cur[KB], gbase[KB];
  __shared__ int part[256];
  __shared__ int tot;
  int tid = threadIdx.x;

  if(blockIdx.x >= GP3){
    // ---- converter blocks ----
    int i = (blockIdx.x - GP3) * 256 + tid;
    if(i >= CVT_END) return;
    if(i < CVT_X)        xb[i] = f2bf(x[i]);
    else if(i < CVT_W1)  W1b[i - CVT_X]    = f2bf(W1[i - CVT_X]);
    else if(i < CVT_WL2) Wl2b[i - CVT_W1]  = f2bf(Wl2[i - CVT_W1]);
    else if(i < CVT_WR2) Wr2b[i - CVT_WL2] = f2bf(Wr2[i - CVT_WL2]);
    else if(i < CVT_WL3) Wl3b[i - CVT_WR2] = f2bf(Wl3[i - CVT_WR2]);
    else if(i < CVT_WR3) Wr3b[i - CVT_WL3] = f2bf(Wr3[i - CVT_WL3]);
    else                 W4b[i - CVT_WR3]  = f2bf(W4[i - CVT_WR3]);
    return;
  }

  // ---- partition blocks ----
  int layer = blockIdx.x % 3;
  int tile = (blockIdx.x / 3) * PT2;
  const int* ei = (layer == 0) ? ei0 : ((layer == 1) ? ei1 : ei2);
  int2* recL = rec + (size_t)layer * KB * RCAP;
  int* gcurL = gcur + layer * KB;
  for(int i = tid; i < KB; i += 256) hist[i] = 0;
  __syncthreads();
  int dst[8], pay[8];
  #pragma unroll
  for(int j = 0; j < 8; j++){
    int e = tile + j * 256 + tid;
    if(e < NE){
      dst[j] = ei[NE + e];
      pay[j] = (layer == 0) ? e : ei[e];   // L0 carries eid; L1/L2 carry src
      atomicAdd(&hist[dst[j] >> SH], 1);
    }
    else dst[j] = -1;
  }
  __syncthreads();
  int c0 = (tid < KB) ? hist[tid] : 0;
  part[tid] = c0;
  __syncthreads();
  for(int d = 1; d < 256; d <<= 1){
    int v = (tid >= d) ? part[tid - d] : 0;
    __syncthreads();
    part[tid] += v;
    __syncthreads();
  }
  if(tid < KB){
    int e = part[tid] - c0;
    ex[tid] = e; cur[tid] = e;
    gbase[tid] = atomicAdd(&gcurL[tid], c0);
  }
  if(tid == 255) tot = part[255];
  __syncthreads();
  #pragma unroll
  for(int j = 0; j < 8; j++){
    if(dst[j] >= 0){
      int b = dst[j] >> SH;
      int s = atomicAdd(&cur[b], 1);
      stage[s] = make_int2(dst[j], pay[j]);
    }
  }
  __syncthreads();
  for(int s = tid; s < tot; s += 256){
    int2 r = stage[s];
    int b = r.x >> SH;
    recL[b * RCAP + gbase[b] + (s - ex[b])] = r;
  }
}

// ---- FUSED 3-layer per-bucket CSR build: 3x196 blocks.
// rec.y: L0 = eid (src gathered from ei0, piecewise-ascending -> L2-friendly);
// L1/L2 = src directly. L0 -> adj2 {src,eid}; L1/L2 -> int adj. ----
__global__ void k_build3(const int2* __restrict__ rec, const int* __restrict__ gcnt,
                         const int* __restrict__ ei0,
                         int2* __restrict__ adj2, int* __restrict__ adjI1, int* __restrict__ adjI2,
                         int* __restrict__ rowbeg3, int* __restrict__ deg3){
  __shared__ int cnt[NPB], cur2[NPB];
  __shared__ int part[256];
  int layer = blockIdx.x % 3;
  int b = blockIdx.x / 3;
  int tid = threadIdx.x;
  int n0 = b << SH;
  int nr = gcnt[layer * KB + b];
  const int2* r = rec + ((size_t)layer * KB + b) * RCAP;
  cnt[tid] = 0;
  __syncthreads();
  for(int k = tid; k < nr; k += 256) atomicAdd(&cnt[r[k].x - n0], 1);
  __syncthreads();
  int c0 = cnt[tid];
  part[tid] = c0;
  __syncthreads();
  for(int d = 1; d < 256; d <<= 1){
    int v = (tid >= d) ? part[tid - d] : 0;
    __syncthreads();
    part[tid] += v;
    __syncthreads();
  }
  int base = part[tid] - c0;
  cur2[tid] = base;
  __syncthreads();
  int n = n0 + tid;
  if(n < NN){ rowbeg3[layer * NN + n] = b * RCAP + base; deg3[layer * NN + n] = c0; }
  for(int k = tid; k < nr; k += 256){
    int2 q = r[k];
    int p = atomicAdd(&cur2[q.x - n0], 1);
    if(layer == 0)      adj2[b * RCAP + p]  = make_int2(ei0[q.y], q.y);
    else if(layer == 1) adjI1[b * RCAP + p] = q.y;
    else                adjI2[b * RCAP + p] = q.y;
  }
}

// ---- fused L0 aggregation (R2/R7-proven): wave per node; 16 lanes/edge, 8 edges/iter.
// lanes 0-7 gather xb row (16B each), lanes 8-15 gather ea row directly (16B each). ----
__global__ void k_aggXE(const int* __restrict__ rowbeg, const int* __restrict__ deg,
                        const int2* __restrict__ adj2,
                        const unsigned short* __restrict__ xb, const float* __restrict__ ea,
                        unsigned short* __restrict__ agg){
  int w = (blockIdx.x * blockDim.x + threadIdx.x) >> 6;
  int lane = threadIdx.x & 63;
  if(w >= NN) return;
  int sub = lane >> 4, li = lane & 15;
  int r0 = rowbeg[w], dg = deg[w], r1 = r0 + dg;
  float acc[8] = {0.f,0.f,0.f,0.f,0.f,0.f,0.f,0.f};
  for(int k = r0; k < r1; k += 8){
    int e0 = k + sub, e1 = k + 4 + sub;
    int i0 = e0 < r1 ? e0 : r1 - 1;
    int i1 = e1 < r1 ? e1 : r1 - 1;
    float m0 = e0 < r1 ? 1.f : 0.f;
    float m1 = e1 < r1 ? 1.f : 0.f;
    int2 a0 = adj2[i0], a1 = adj2[i1];
    if(li < 8){
      uint4 v0 = *(const uint4*)(xb + (size_t)a0.x * 64 + li * 8);
      uint4 v1 = *(const uint4*)(xb + (size_t)a1.x * 64 + li * 8);
      acc[0] += m0 * bf2f(v0.x & 0xffffu); acc[1] += m0 * bf2f(v0.x >> 16);
      acc[2] += m0 * bf2f(v0.y & 0xffffu); acc[3] += m0 * bf2f(v0.y >> 16);
      acc[4] += m0 * bf2f(v0.z & 0xffffu); acc[5] += m0 * bf2f(v0.z >> 16);
      acc[6] += m0 * bf2f(v0.w & 0xffffu); acc[7] += m0 * bf2f(v0.w >> 16);
      acc[0] += m1 * bf2f(v1.x & 0xffffu); acc[1] += m1 * bf2f(v1.x >> 16);
      acc[2] += m1 * bf2f(v1.y & 0xffffu); acc[3] += m1 * bf2f(v1.y >> 16);
      acc[4] += m1 * bf2f(v1.z & 0xffffu); acc[5] += m1 * bf2f(v1.z >> 16);
      acc[6] += m1 * bf2f(v1.w & 0xffffu); acc[7] += m1 * bf2f(v1.w >> 16);
    } else {
      int j = li - 8;
      float4 p0 = *(const float4*)(ea + (size_t)a0.y * 32 + j * 4);
      float4 p1 = *(const float4*)(ea + (size_t)a1.y * 32 + j * 4);
      acc[0] += m0 * p0.x; acc[1] += m0 * p0.y;
      acc[2] += m0 * p0.z; acc[3] += m0 * p0.w;
      acc[0] += m1 * p1.x; acc[1] += m1 * p1.y;
      acc[2] += m1 * p1.z; acc[3] += m1 * p1.w;
    }
  }
  #pragma unroll
  for(int d = 16; d < 64; d <<= 1){
    #pragma unroll
    for(int i = 0; i < 8; i++) acc[i] += __shfl_xor(acc[i], d, 64);
  }
  if(sub == 0){
    float inv = 1.0f / (float)(dg > 0 ? dg : 1);
    if(li < 8){
      unsigned int q0 = (unsigned int)f2bf(acc[0]*inv) | ((unsigned int)f2bf(acc[1]*inv) << 16);
      unsigned int q1 = (unsigned int)f2bf(acc[2]*inv) | ((unsigned int)f2bf(acc[3]*inv) << 16);
      unsigned int q2 = (unsigned int)f2bf(acc[4]*inv) | ((unsigned int)f2bf(acc[5]*inv) << 16);
      unsigned int q3 = (unsigned int)f2bf(acc[6]*inv) | ((unsigned int)f2bf(acc[7]*inv) << 16);
      *(uint4*)(agg + (size_t)w * 96 + li * 8) = make_uint4(q0, q1, q2, q3);
    } else {
      int j = li - 8;
      unsigned int q0 = (unsigned int)f2bf(acc[0]*inv) | ((unsigned int)f2bf(acc[1]*inv) << 16);
      unsigned int q1 = (unsigned int)f2bf(acc[2]*inv) | ((unsigned int)f2bf(acc[3]*inv) << 16);
      *(uint2*)(agg + (size_t)w * 96 + 64 + j * 4) = make_uint2(q0, q1);
    }
  }
}

// ---- h aggregation (R2-proven): wave per node; 16 lanes/edge, 8 edges/iter ----
__global__ void k_aggH(const int* __restrict__ rowbeg, const int* __restrict__ deg,
                       const int* __restrict__ adj,
                       const unsigned short* __restrict__ h, unsigned short* __restrict__ agg){
  int w = (blockIdx.x * blockDim.x + threadIdx.x) >> 6;
  int lane = threadIdx.x & 63;
  if(w >= NN) return;
  int sub = lane >> 4, li = lane & 15;
  int r0 = rowbeg[w], dg = deg[w], r1 = r0 + dg;
  float acc[8] = {0.f,0.f,0.f,0.f,0.f,0.f,0.f,0.f};
  for(int k = r0; k < r1; k += 8){
    int e0 = k + sub, e1 = k + 4 + sub;
    int i0 = e0 < r1 ? e0 : r1 - 1;
    int i1 = e1 < r1 ? e1 : r1 - 1;
    float m0 = e0 < r1 ? 1.f : 0.f;
    float m1 = e1 < r1 ? 1.f : 0.f;
    int s0 = adj[i0], s1 = adj[i1];
    uint4 v0 = *(const uint4*)(h + (size_t)s0 * 128 + li * 8);
    uint4 v1 = *(const uint4*)(h + (size_t)s1 * 128 + li * 8);
    acc[0] += m0 * bf2f(v0.x & 0xffffu); acc[1] += m0 * bf2f(v0.x >> 16);
    acc[2] += m0 * bf2f(v0.y & 0xffffu); acc[3] += m0 * bf2f(v0.y >> 16);
    acc[4] += m0 * bf2f(v0.z & 0xffffu); acc[5] += m0 * bf2f(v0.z >> 16);
    acc[6] += m0 * bf2f(v0.w & 0xffffu); acc[7] += m0 * bf2f(v0.w >> 16);
    acc[0] += m1 * bf2f(v1.x & 0xffffu); acc[1] += m1 * bf2f(v1.x >> 16);
    acc[2] += m1 * bf2f(v1.y & 0xffffu); acc[3] += m1 * bf2f(v1.y >> 16);
    acc[4] += m1 * bf2f(v1.z & 0xffffu); acc[5] += m1 * bf2f(v1.z >> 16);
    acc[6] += m1 * bf2f(v1.w & 0xffffu); acc[7] += m1 * bf2f(v1.w >> 16);
  }
  #pragma unroll
  for(int d = 16; d < 64; d <<= 1){
    #pragma unroll
    for(int i = 0; i < 8; i++) acc[i] += __shfl_xor(acc[i], d, 64);
  }
  if(sub == 0){
    float inv = 1.0f / (float)(dg > 0 ? dg : 1);
    unsigned int p0 = (unsigned int)f2bf(acc[0]*inv) | ((unsigned int)f2bf(acc[1]*inv) << 16);
    unsigned int p1 = (unsigned int)f2bf(acc[2]*inv) | ((unsigned int)f2bf(acc[3]*inv) << 16);
    unsigned int p2 = (unsigned int)f2bf(acc[4]*inv) | ((unsigned int)f2bf(acc[5]*inv) << 16);
    unsigned int p3 = (unsigned int)f2bf(acc[6]*inv) | ((unsigned int)f2bf(acc[7]*inv) << 16);
    *(uint4*)(agg + (size_t)w * 128 + li * 8) = make_uint4(p0, p1, p2, p3);
  }
}

// conv1 dense part: h1 = relu(bn(relu(mask_deg(agg @ W1^T + b1))))
__global__ void k_lin1(const unsigned short* __restrict__ agg, const unsigned short* __restrict__ W1,
                       const float* __restrict__ b1,
                       const float* __restrict__ g1, const float* __restrict__ be1,
                       const float* __restrict__ m1, const float* __restrict__ v1,
                       const int* __restrict__ deg, unsigned short* __restrict__ h1){
  int wave = (blockIdx.x * blockDim.x + threadIdx.x) >> 6;
  int lane = threadIdx.x & 63;
  int mt = wave >> 3, nt = wave & 7;
  if(mt >= 3125) return;
  int node0 = mt * 16;
  int col = lane & 15, quad = lane >> 4;
  int o = nt * 16 + col;
  int arow = node0 + col;
  floatx4 acc = {0.f, 0.f, 0.f, 0.f};
  #pragma unroll
  for(int kc = 0; kc < 3; kc++){
    bf16x8 a = *(const bf16x8*)(agg + arow * 96 + kc * 32 + quad * 8);
    bf16x8 b = *(const bf16x8*)(W1 + o * 96 + kc * 32 + quad * 8);
    acc = __builtin_amdgcn_mfma_f32_16x16x32_bf16(a, b, acc, 0, 0, 0);
  }
  float bb = b1[o];
  float sc = g1[o] * rsqrtf(v1[o] + EPS);
  float mv = m1[o], bev = be1[o];
  #pragma unroll
  for(int r = 0; r < 4; r++){
    int node = node0 + quad * 4 + r;
    float pre = (deg[node] > 0) ? (acc[r] + bb) : 0.0f;   // ref: empty segment -> mean 0, bias never added
    float t = fmaxf(pre, 0.f);
    float bn = sc * (t - mv) + bev;
    h1[node * 128 + o] = f2bf(fmaxf(bn, 0.f));
  }
}

// SAGE: hout = relu(bn(agg @ Wl^T + bl + hin @ Wr^T))
__global__ void k_sage(const unsigned short* __restrict__ agg, const unsigned short* __restrict__ hin,
                       const unsigned short* __restrict__ Wl, const float* __restrict__ bl,
                       const unsigned short* __restrict__ Wr,
                       const float* __restrict__ g, const float* __restrict__ be,
                       const float* __restrict__ m, const float* __restrict__ v,
                       unsigned short* __restrict__ hout){
  int wave = (blockIdx.x * blockDim.x + threadIdx.x) >> 6;
  int lane = threadIdx.x & 63;
  int mt = wave >> 3, nt = wave & 7;
  if(mt >= 3125) return;
  int node0 = mt * 16;
  int col = lane & 15, quad = lane >> 4;
  int o = nt * 16 + col;
  int arow = node0 + col;
  floatx4 acc = {0.f, 0.f, 0.f, 0.f};
  #pragma unroll
  for(int kc = 0; kc < 4; kc++){
    bf16x8 a = *(const bf16x8*)(agg + arow * 128 + kc * 32 + quad * 8);
    bf16x8 b = *(const bf16x8*)(Wl + o * 128 + kc * 32 + quad * 8);
    acc = __builtin_amdgcn_mfma_f32_16x16x32_bf16(a, b, acc, 0, 0, 0);
  }
  #pragma unroll
  for(int kc = 0; kc < 4; kc++){
    bf16x8 a = *(const bf16x8*)(hin + arow * 128 + kc * 32 + quad * 8);
    bf16x8 b = *(const bf16x8*)(Wr + o * 128 + kc * 32 + quad * 8);
    acc = __builtin_amdgcn_mfma_f32_16x16x32_bf16(a, b, acc, 0, 0, 0);
  }
  float blv = bl[o];
  float sc = g[o] * rsqrtf(v[o] + EPS);
  float mv = m[o], bev = be[o];
  #pragma unroll
  for(int r = 0; r < 4; r++){
    int node = node0 + quad * 4 + r;
    float pre = acc[r] + blv;
    float bn = sc * (pre - mv) + bev;
    hout[node * 128 + o] = f2bf(fmaxf(bn, 0.f));
  }
}

// readout: z = relu([h3 | x] @ W4^T + b4) (64), out = z @ W5^T + b5  (f32 out)
__global__ void k_readout(const unsigned short* __restrict__ h3, const unsigned short* __restrict__ xb,
                          const unsigned short* __restrict__ W4, const float* __restrict__ b4,
                          const float* __restrict__ W5, const float* __restrict__ b5,
                          float* __restrict__ out){
  int wave = (blockIdx.x * blockDim.x + threadIdx.x) >> 6;
  int lane = threadIdx.x & 63;
  if(wave >= 3125) return;
  int node0 = wave * 16;
  int col = lane & 15, quad = lane >> 4;
  int arow = node0 + col;
  float partial[4] = {0.f, 0.f, 0.f, 0.f};
  #pragma unroll
  for(int nt = 0; nt < 4; nt++){
    int o = nt * 16 + col;
    floatx4 acc = {0.f, 0.f, 0.f, 0.f};
    #pragma unroll
    for(int kc = 0; kc < 4; kc++){
      bf16x8 a = *(const bf16x8*)(h3 + arow * 128 + kc * 32 + quad * 8);
      bf16x8 b = *(const bf16x8*)(W4 + o * 192 + kc * 32 + quad * 8);
      acc = __builtin_amdgcn_mfma_f32_16x16x32_bf16(a, b, acc, 0, 0, 0);
    }
    #pragma unroll
    for(int kc = 0; kc < 2; kc++){
      bf16x8 a = *(const bf16x8*)(xb + arow * 64 + kc * 32 + quad * 8);
      bf16x8 b = *(const bf16x8*)(W4 + o * 192 + 128 + kc * 32 + quad * 8);
      acc = __builtin_amdgcn_mfma_f32_16x16x32_bf16(a, b, acc, 0, 0, 0);
    }
    float bb = b4[o];
    float w5 = W5[o];
    #pragma unroll
    for(int r = 0; r < 4; r++)
      partial[r] += fmaxf(acc[r] + bb, 0.f) * w5;
  }
  #pragma unroll
  for(int d = 1; d < 16; d <<= 1){
    #pragma unroll
    for(int r = 0; r < 4; r++)
      partial[r] += __shfl_xor(partial[r], d, 64);
  }
  if(col == 0){
    float b5f = b5[0];
    #pragma unroll
    for(int r = 0; r < 4; r++)
      out[node0 + quad * 4 + r] = partial[r] + b5f;
  }
}

extern "C" void kernel_launch(void* const* d_in, const int* in_sizes, int n_in,
                              void* d_out, int out_size, void* d_ws, size_t ws_size,
                              hipStream_t stream) {
  const float* x   = (const float*)d_in[0];
  const int* ei0   = (const int*)d_in[1];
  const int* ei1   = (const int*)d_in[2];
  const int* ei2   = (const int*)d_in[3];
  const float* ea  = (const float*)d_in[4];
  const float* W1  = (const float*)d_in[5];
  const float* b1  = (const float*)d_in[6];
  const float* g1  = (const float*)d_in[7];
  const float* be1 = (const float*)d_in[8];
  const float* m1  = (const float*)d_in[9];
  const float* v1  = (const float*)d_in[10];
  const float* Wl2 = (const float*)d_in[11];
  const float* bl2 = (const float*)d_in[12];
  const float* Wr2 = (const float*)d_in[13];
  const float* g2  = (const float*)d_in[14];
  const float* be2 = (const float*)d_in[15];
  const float* m2  = (const float*)d_in[16];
  const float* v2  = (const float*)d_in[17];
  const float* Wl3 = (const float*)d_in[18];
  const float* bl3 = (const float*)d_in[19];
  const float* Wr3 = (const float*)d_in[20];
  const float* g3  = (const float*)d_in[21];
  const float* be3 = (const float*)d_in[22];
  const float* m3  = (const float*)d_in[23];
  const float* v3  = (const float*)d_in[24];
  const float* W4  = (const float*)d_in[25];
  const float* b4  = (const float*)d_in[26];
  const float* W5  = (const float*)d_in[27];
  const float* b5  = (const float*)d_in[28];

  char* ws = (char*)d_ws;
  size_t off = 0;
  auto alloc = [&](size_t bytes) -> void* {
    void* p = (void*)(ws + off);
    off += (bytes + 255) & ~(size_t)255;
    return p;
  };
  int* gcur    = (int*)alloc(3 * KB * sizeof(int));
  int* rowbeg3 = (int*)alloc(3 * NN * sizeof(int));
  int* deg3    = (int*)alloc(3 * NN * sizeof(int));
  // UNION region: phase 1 = rec (3 layers int2, 21.2MB); phase 2 (from k_lin1 on,
  // rec dead after k_build3) = h1/aggH/h2 (38.4MB). size = max = 38.4MB.
  char* uni    = (char*)alloc((size_t)3 * NN * 128 * 2);
  int2* adj2   = (int2*)alloc((size_t)KB * RCAP * 8);
  int* adjI1   = (int*)alloc((size_t)KB * RCAP * 4);
  int* adjI2   = (int*)alloc((size_t)KB * RCAP * 4);
  unsigned short* agg1 = (unsigned short*)alloc((size_t)NN * 96 * 2);
  unsigned short* xb   = (unsigned short*)alloc((size_t)NN * 64 * 2);
  unsigned short* W1b  = (unsigned short*)alloc(12288 * 2);
  unsigned short* Wl2b = (unsigned short*)alloc(16384 * 2);
  unsigned short* Wr2b = (unsigned short*)alloc(16384 * 2);
  unsigned short* Wl3b = (unsigned short*)alloc(16384 * 2);
  unsigned short* Wr3b = (unsigned short*)alloc(16384 * 2);
  unsigned short* W4b  = (unsigned short*)alloc(12288 * 2);

  // phase-1 alias
  int2* recDS = (int2*)uni;
  // phase-2 aliases (h3 reuses h1's slot; ordering-proven in R6/R7)
  unsigned short* h1   = (unsigned short*)uni;
  unsigned short* aggH = h1 + (size_t)NN * 128;
  unsigned short* h2   = h1 + (size_t)2 * NN * 128;
  unsigned short* h3   = h1;

  int* rb0 = rowbeg3;            int* dg0 = deg3;
  int* rb1 = rowbeg3 + NN;       int* dg1 = deg3 + NN;
  int* rb2 = rowbeg3 + 2 * NN;   int* dg2 = deg3 + 2 * NN;

  const int gB3   = 3 * KB;                    // 588
  const int gAgg  = (NN * 64) / 256;           // 12500
  const int gTile = (3125 * 8 * 64) / 256;     // 6250
  const int gRead = (3125 * 64 + 255) / 256;   // 782

  // zero bucket cursors (read via atomicAdd inside the fused dispatch)
  hipMemsetAsync(gcur, 0, 3 * KB * sizeof(int), stream);

  // ---- fused: 3-layer partition + f32->bf16 conversion in one dispatch ----
  k_part3cvt<<<GP3 + GCVT, 256, 0, stream>>>(ei0, ei1, ei2, gcur, recDS,
                                             x, W1, Wl2, Wr2, Wl3, Wr3, W4,
                                             xb, W1b, Wl2b, Wr2b, Wl3b, Wr3b, W4b);
  k_build3<<<gB3, 256, 0, stream>>>(recDS, gcur, ei0, adj2, adjI1, adjI2, rowbeg3, deg3);

  // ---- layer 1 (conv1) ----
  k_aggXE<<<gAgg, 256, 0, stream>>>(rb0, dg0, adj2, xb, ea, agg1);
  k_lin1<<<gTile, 256, 0, stream>>>(agg1, W1b, b1, g1, be1, m1, v1, dg0, h1);

  // ---- layer 2 (SAGE) ----
  k_aggH<<<gAgg, 256, 0, stream>>>(rb1, dg1, adjI1, h1, aggH);
  k_sage<<<gTile, 256, 0, stream>>>(aggH, h1, Wl2b, bl2, Wr2b, g2, be2, m2, v2, h2);

  // ---- layer 3 (SAGE) ----
  k_aggH<<<gAgg, 256, 0, stream>>>(rb2, dg2, adjI2, h2, aggH);
  k_sage<<<gTile, 256, 0, stream>>>(aggH, h2, Wl3b, bl3, Wr3b, g3, be3, m3, v3, h3);

  // ---- readout ----
  k_readout<<<gRead, 256, 0, stream>>>(h3, xb, W4b, b4, W5, b5, (float*)d_out);

  (void)in_sizes; (void)n_in; (void)out_size; (void)ws_size;
}

// Round 10
// 470.885 us; speedup vs baseline: 1.2302x; 1.0584x over previous
//
#include <hip/hip_runtime.h>
#include <hip/hip_bf16.h>
#include <stdint.h>

#define NN 50000
#define NE 800000
#define EPS 1e-5f

// CSR bucket params
#define KB 196       // buckets = ceil(NN / NPB)
#define SH 8         // bucket = dst >> SH
#define NPB 256      // nodes per bucket
#define RCAP 4500    // slots per bucket (mean 4082, +6.6 sigma)
#define PT2 2048     // edges per DS-partition block
#define NT2 391      // tiles per layer = ceil(NE/PT2)

#define PADL 104     // LDS row stride (shorts) for 96-dim agg rows (2-way bank alias)
#define PADS 136     // LDS row stride (shorts) for 128-dim agg rows

typedef __attribute__((ext_vector_type(8))) short bf16x8;
typedef __attribute__((ext_vector_type(4))) float floatx4;

static __device__ __forceinline__ float bf2f(unsigned int u){
  union { unsigned int i; float f; } c; c.i = u << 16; return c.f;
}
static __device__ __forceinline__ unsigned short f2bf(float f){
  union { float f; unsigned int i; } c; c.f = f;
  unsigned int x = c.i;
  return (unsigned short)((x + 0x7fffu + ((x >> 16) & 1u)) >> 16);
}

// fused f32 -> bf16 converter for x + the 6 GEMM weight matrices; also zeros bucket cursors
#define CVT_X   3200000
#define CVT_W1  3212288
#define CVT_WL2 3228672
#define CVT_WR2 3245056
#define CVT_WL3 3261440
#define CVT_WR3 3277824
#define CVT_END 3290112
__global__ void k_cvt_all(const float* __restrict__ x,  const float* __restrict__ W1,
                          const float* __restrict__ Wl2, const float* __restrict__ Wr2,
                          const float* __restrict__ Wl3, const float* __restrict__ Wr3,
                          const float* __restrict__ W4,
                          unsigned short* __restrict__ xb,  unsigned short* __restrict__ W1b,
                          unsigned short* __restrict__ Wl2b, unsigned short* __restrict__ Wr2b,
                          unsigned short* __restrict__ Wl3b, unsigned short* __restrict__ Wr3b,
                          unsigned short* __restrict__ W4b, int* __restrict__ gcur){
  int i = blockIdx.x * 256 + threadIdx.x;
  if(i >= CVT_END) return;
  if(i < 3 * KB) gcur[i] = 0;
  if(i < CVT_X)        xb[i] = f2bf(x[i]);
  else if(i < CVT_W1)  W1b[i - CVT_X]    = f2bf(W1[i - CVT_X]);
  else if(i < CVT_WL2) Wl2b[i - CVT_W1]  = f2bf(Wl2[i - CVT_W1]);
  else if(i < CVT_WR2) Wr2b[i - CVT_WL2] = f2bf(Wr2[i - CVT_WL2]);
  else if(i < CVT_WL3) Wl3b[i - CVT_WR2] = f2bf(Wl3[i - CVT_WR2]);
  else if(i < CVT_WR3) Wr3b[i - CVT_WL3] = f2bf(Wr3[i - CVT_WL3]);
  else                 W4b[i - CVT_WR3]  = f2bf(W4[i - CVT_WR3]);
}

// ---- FUSED 3-layer partition (R9-lean): layer = blk%3; L0 stages {dst,eid}
// (src recovered in build3 via ei0[eid]); L1/L2 stage {dst,src}. ----
__global__ void k_part3(const int* __restrict__ ei0, const int* __restrict__ ei1,
                        const int* __restrict__ ei2, int* __restrict__ gcur,
                        int2* __restrict__ rec){
  __shared__ int2 stage[PT2];
  __shared__ int hist[KB], ex[KB], cur[KB], gbase[KB];
  __shared__ int part[256];
  __shared__ int tot;
  int tid = threadIdx.x;
  int layer = blockIdx.x % 3;
  int tile = (blockIdx.x / 3) * PT2;
  const int* ei = (layer == 0) ? ei0 : ((layer == 1) ? ei1 : ei2);
  int2* recL = rec + (size_t)layer * KB * RCAP;
  int* gcurL = gcur + layer * KB;
  for(int i = tid; i < KB; i += 256) hist[i] = 0;
  __syncthreads();
  int dst[8], pay[8];
  #pragma unroll
  for(int j = 0; j < 8; j++){
    int e = tile + j * 256 + tid;
    if(e < NE){
      dst[j] = ei[NE + e];
      pay[j] = (layer == 0) ? e : ei[e];   // L0 carries eid; L1/L2 carry src
      atomicAdd(&hist[dst[j] >> SH], 1);
    }
    else dst[j] = -1;
  }
  __syncthreads();
  int c0 = (tid < KB) ? hist[tid] : 0;
  part[tid] = c0;
  __syncthreads();
  for(int d = 1; d < 256; d <<= 1){
    int v = (tid >= d) ? part[tid - d] : 0;
    __syncthreads();
    part[tid] += v;
    __syncthreads();
  }
  if(tid < KB){
    int e = part[tid] - c0;
    ex[tid] = e; cur[tid] = e;
    gbase[tid] = atomicAdd(&gcurL[tid], c0);
  }
  if(tid == 255) tot = part[255];
  __syncthreads();
  #pragma unroll
  for(int j = 0; j < 8; j++){
    if(dst[j] >= 0){
      int b = dst[j] >> SH;
      int s = atomicAdd(&cur[b], 1);
      stage[s] = make_int2(dst[j], pay[j]);
    }
  }
  __syncthreads();
  for(int s = tid; s < tot; s += 256){
    int2 r = stage[s];
    int b = r.x >> SH;
    recL[b * RCAP + gbase[b] + (s - ex[b])] = r;
  }
}

// ---- FUSED 3-layer per-bucket CSR build (R9-lean). ----
__global__ void k_build3(const int2* __restrict__ rec, const int* __restrict__ gcnt,
                         const int* __restrict__ ei0,
                         int2* __restrict__ adj2, int* __restrict__ adjI1, int* __restrict__ adjI2,
                         int* __restrict__ rowbeg3, int* __restrict__ deg3){
  __shared__ int cnt[NPB], cur2[NPB];
  __shared__ int part[256];
  int layer = blockIdx.x % 3;
  int b = blockIdx.x / 3;
  int tid = threadIdx.x;
  int n0 = b << SH;
  int nr = gcnt[layer * KB + b];
  const int2* r = rec + ((size_t)layer * KB + b) * RCAP;
  cnt[tid] = 0;
  __syncthreads();
  for(int k = tid; k < nr; k += 256) atomicAdd(&cnt[r[k].x - n0], 1);
  __syncthreads();
  int c0 = cnt[tid];
  part[tid] = c0;
  __syncthreads();
  for(int d = 1; d < 256; d <<= 1){
    int v = (tid >= d) ? part[tid - d] : 0;
    __syncthreads();
    part[tid] += v;
    __syncthreads();
  }
  int base = part[tid] - c0;
  cur2[tid] = base;
  __syncthreads();
  int n = n0 + tid;
  if(n < NN){ rowbeg3[layer * NN + n] = b * RCAP + base; deg3[layer * NN + n] = c0; }
  for(int k = tid; k < nr; k += 256){
    int2 q = r[k];
    int p = atomicAdd(&cur2[q.x - n0], 1);
    if(layer == 0)      adj2[b * RCAP + p]  = make_int2(ei0[q.y], q.y);
    else if(layer == 1) adjI1[b * RCAP + p] = q.y;
    else                adjI2[b * RCAP + p] = q.y;
  }
}

// ---- FUSED L0 aggregation + conv1 linear: 1024 threads = 16 waves per block.
// Waves 0-15: aggregate node node0+wv (16 lanes/edge: lanes 0-7 xb rows, 8-15 ea
// rows) -> bf16 mean row into LDS (pad 104 -> 2-way bank alias, free).
// Barrier. Waves 0-7: lin1 MFMA with A-fragment from LDS (agg1 buffer deleted). ----
__global__ __launch_bounds__(1024) void k_aggXElin(
                        const int* __restrict__ rowbeg, const int* __restrict__ deg,
                        const int2* __restrict__ adj2,
                        const unsigned short* __restrict__ xb, const float* __restrict__ ea,
                        const unsigned short* __restrict__ W1, const float* __restrict__ b1,
                        const float* __restrict__ g1, const float* __restrict__ be1,
                        const float* __restrict__ m1, const float* __restrict__ v1,
                        unsigned short* __restrict__ h1){
  __shared__ unsigned short sA[16][PADL];
  int tid = threadIdx.x;
  int wv = tid >> 6, lane = tid & 63;
  int node0 = blockIdx.x * 16;
  int w = node0 + wv;
  int sub = lane >> 4, li = lane & 15;
  int r0 = rowbeg[w], dg = deg[w], r1 = r0 + dg;
  float acc[8] = {0.f,0.f,0.f,0.f,0.f,0.f,0.f,0.f};
  for(int k = r0; k < r1; k += 8){
    int e0 = k + sub, e1 = k + 4 + sub;
    int i0 = e0 < r1 ? e0 : r1 - 1;
    int i1 = e1 < r1 ? e1 : r1 - 1;
    float m0 = e0 < r1 ? 1.f : 0.f;
    float m1f = e1 < r1 ? 1.f : 0.f;
    int2 a0 = adj2[i0], a1 = adj2[i1];
    if(li < 8){
      uint4 v0 = *(const uint4*)(xb + (size_t)a0.x * 64 + li * 8);
      uint4 v1 = *(const uint4*)(xb + (size_t)a1.x * 64 + li * 8);
      acc[0] += m0 * bf2f(v0.x & 0xffffu); acc[1] += m0 * bf2f(v0.x >> 16);
      acc[2] += m0 * bf2f(v0.y & 0xffffu); acc[3] += m0 * bf2f(v0.y >> 16);
      acc[4] += m0 * bf2f(v0.z & 0xffffu); acc[5] += m0 * bf2f(v0.z >> 16);
      acc[6] += m0 * bf2f(v0.w & 0xffffu); acc[7] += m0 * bf2f(v0.w >> 16);
      acc[0] += m1f * bf2f(v1.x & 0xffffu); acc[1] += m1f * bf2f(v1.x >> 16);
      acc[2] += m1f * bf2f(v1.y & 0xffffu); acc[3] += m1f * bf2f(v1.y >> 16);
      acc[4] += m1f * bf2f(v1.z & 0xffffu); acc[5] += m1f * bf2f(v1.z >> 16);
      acc[6] += m1f * bf2f(v1.w & 0xffffu); acc[7] += m1f * bf2f(v1.w >> 16);
    } else {
      int j = li - 8;
      float4 p0 = *(const float4*)(ea + (size_t)a0.y * 32 + j * 4);
      float4 p1 = *(const float4*)(ea + (size_t)a1.y * 32 + j * 4);
      acc[0] += m0 * p0.x; acc[1] += m0 * p0.y;
      acc[2] += m0 * p0.z; acc[3] += m0 * p0.w;
      acc[0] += m1f * p1.x; acc[1] += m1f * p1.y;
      acc[2] += m1f * p1.z; acc[3] += m1f * p1.w;
    }
  }
  #pragma unroll
  for(int d = 16; d < 64; d <<= 1){
    #pragma unroll
    for(int i = 0; i < 8; i++) acc[i] += __shfl_xor(acc[i], d, 64);
  }
  if(sub == 0){
    float inv = 1.0f / (float)(dg > 0 ? dg : 1);
    if(li < 8){
      unsigned int q0 = (unsigned int)f2bf(acc[0]*inv) | ((unsigned int)f2bf(acc[1]*inv) << 16);
      unsigned int q1 = (unsigned int)f2bf(acc[2]*inv) | ((unsigned int)f2bf(acc[3]*inv) << 16);
      unsigned int q2 = (unsigned int)f2bf(acc[4]*inv) | ((unsigned int)f2bf(acc[5]*inv) << 16);
      unsigned int q3 = (unsigned int)f2bf(acc[6]*inv) | ((unsigned int)f2bf(acc[7]*inv) << 16);
      *(uint4*)&sA[wv][li * 8] = make_uint4(q0, q1, q2, q3);
    } else {
      int j = li - 8;
      unsigned int q0 = (unsigned int)f2bf(acc[0]*inv) | ((unsigned int)f2bf(acc[1]*inv) << 16);
      unsigned int q1 = (unsigned int)f2bf(acc[2]*inv) | ((unsigned int)f2bf(acc[3]*inv) << 16);
      *(uint2*)&sA[wv][64 + j * 4] = make_uint2(q0, q1);
    }
  }
  __syncthreads();
  if(wv < 8){
    int col = lane & 15, quad = lane >> 4;
    int o = wv * 16 + col;
    floatx4 acc2 = {0.f, 0.f, 0.f, 0.f};
    #pragma unroll
    for(int kc = 0; kc < 3; kc++){
      bf16x8 a = *(const bf16x8*)&sA[col][kc * 32 + quad * 8];
      bf16x8 b = *(const bf16x8*)(W1 + o * 96 + kc * 32 + quad * 8);
      acc2 = __builtin_amdgcn_mfma_f32_16x16x32_bf16(a, b, acc2, 0, 0, 0);
    }
    float bb = b1[o];
    float sc = g1[o] * rsqrtf(v1[o] + EPS);
    float mv = m1[o], bev = be1[o];
    #pragma unroll
    for(int r = 0; r < 4; r++){
      int node = node0 + quad * 4 + r;
      float pre = (deg[node] > 0) ? (acc2[r] + bb) : 0.0f;  // ref: empty segment -> mean 0
      float t = fmaxf(pre, 0.f);
      float bn = sc * (t - mv) + bev;
      h1[node * 128 + o] = f2bf(fmaxf(bn, 0.f));
    }
  }
}

// ---- FUSED h aggregation + SAGE linear: 16 waves aggregate -> LDS (pad 136),
// barrier, 8 waves MFMA (A from LDS, hin/W from global). aggH buffer deleted. ----
__global__ __launch_bounds__(1024) void k_aggsage(
                       const int* __restrict__ rowbeg, const int* __restrict__ deg,
                       const int* __restrict__ adj,
                       const unsigned short* __restrict__ hin,
                       const unsigned short* __restrict__ Wl, const float* __restrict__ bl,
                       const unsigned short* __restrict__ Wr,
                       const float* __restrict__ g, const float* __restrict__ be,
                       const float* __restrict__ m, const float* __restrict__ v,
                       unsigned short* __restrict__ hout){
  __shared__ unsigned short sA[16][PADS];
  int tid = threadIdx.x;
  int wv = tid >> 6, lane = tid & 63;
  int node0 = blockIdx.x * 16;
  int w = node0 + wv;
  int sub = lane >> 4, li = lane & 15;
  int r0 = rowbeg[w], dg = deg[w], r1 = r0 + dg;
  float acc[8] = {0.f,0.f,0.f,0.f,0.f,0.f,0.f,0.f};
  for(int k = r0; k < r1; k += 8){
    int e0 = k + sub, e1 = k + 4 + sub;
    int i0 = e0 < r1 ? e0 : r1 - 1;
    int i1 = e1 < r1 ? e1 : r1 - 1;
    float m0 = e0 < r1 ? 1.f : 0.f;
    float m1f = e1 < r1 ? 1.f : 0.f;
    int s0 = adj[i0], s1 = adj[i1];
    uint4 v0 = *(const uint4*)(hin + (size_t)s0 * 128 + li * 8);
    uint4 v1 = *(const uint4*)(hin + (size_t)s1 * 128 + li * 8);
    acc[0] += m0 * bf2f(v0.x & 0xffffu); acc[1] += m0 * bf2f(v0.x >> 16);
    acc[2] += m0 * bf2f(v0.y & 0xffffu); acc[3] += m0 * bf2f(v0.y >> 16);
    acc[4] += m0 * bf2f(v0.z & 0xffffu); acc[5] += m0 * bf2f(v0.z >> 16);
    acc[6] += m0 * bf2f(v0.w & 0xffffu); acc[7] += m0 * bf2f(v0.w >> 16);
    acc[0] += m1f * bf2f(v1.x & 0xffffu); acc[1] += m1f * bf2f(v1.x >> 16);
    acc[2] += m1f * bf2f(v1.y & 0xffffu); acc[3] += m1f * bf2f(v1.y >> 16);
    acc[4] += m1f * bf2f(v1.z & 0xffffu); acc[5] += m1f * bf2f(v1.z >> 16);
    acc[6] += m1f * bf2f(v1.w & 0xffffu); acc[7] += m1f * bf2f(v1.w >> 16);
  }
  #pragma unroll
  for(int d = 16; d < 64; d <<= 1){
    #pragma unroll
    for(int i = 0; i < 8; i++) acc[i] += __shfl_xor(acc[i], d, 64);
  }
  if(sub == 0){
    float inv = 1.0f / (float)(dg > 0 ? dg : 1);
    unsigned int p0 = (unsigned int)f2bf(acc[0]*inv) | ((unsigned int)f2bf(acc[1]*inv) << 16);
    unsigned int p1 = (unsigned int)f2bf(acc[2]*inv) | ((unsigned int)f2bf(acc[3]*inv) << 16);
    unsigned int p2 = (unsigned int)f2bf(acc[4]*inv) | ((unsigned int)f2bf(acc[5]*inv) << 16);
    unsigned int p3 = (unsigned int)f2bf(acc[6]*inv) | ((unsigned int)f2bf(acc[7]*inv) << 16);
    *(uint4*)&sA[wv][li * 8] = make_uint4(p0, p1, p2, p3);
  }
  __syncthreads();
  if(wv < 8){
    int col = lane & 15, quad = lane >> 4;
    int o = wv * 16 + col;
    int arow = node0 + col;
    floatx4 acc2 = {0.f, 0.f, 0.f, 0.f};
    #pragma unroll
    for(int kc = 0; kc < 4; kc++){
      bf16x8 a = *(const bf16x8*)&sA[col][kc * 32 + quad * 8];
      bf16x8 b = *(const bf16x8*)(Wl + o * 128 + kc * 32 + quad * 8);
      acc2 = __builtin_amdgcn_mfma_f32_16x16x32_bf16(a, b, acc2, 0, 0, 0);
    }
    #pragma unroll
    for(int kc = 0; kc < 4; kc++){
      bf16x8 a = *(const bf16x8*)(hin + arow * 128 + kc * 32 + quad * 8);
      bf16x8 b = *(const bf16x8*)(Wr + o * 128 + kc * 32 + quad * 8);
      acc2 = __builtin_amdgcn_mfma_f32_16x16x32_bf16(a, b, acc2, 0, 0, 0);
    }
    float blv = bl[o];
    float sc = g[o] * rsqrtf(v[o] + EPS);
    float mv = m[o], bev = be[o];
    #pragma unroll
    for(int r = 0; r < 4; r++){
      int node = node0 + quad * 4 + r;
      float pre = acc2[r] + blv;
      float bn = sc * (pre - mv) + bev;
      hout[node * 128 + o] = f2bf(fmaxf(bn, 0.f));
    }
  }
}

// readout: z = relu([h3 | x] @ W4^T + b4) (64), out = z @ W5^T + b5  (f32 out)
__global__ void k_readout(const unsigned short* __restrict__ h3, const unsigned short* __restrict__ xb,
                          const unsigned short* __restrict__ W4, const float* __restrict__ b4,
                          const float* __restrict__ W5, const float* __restrict__ b5,
                          float* __restrict__ out){
  int wave = (blockIdx.x * blockDim.x + threadIdx.x) >> 6;
  int lane = threadIdx.x & 63;
  if(wave >= 3125) return;
  int node0 = wave * 16;
  int col = lane & 15, quad = lane >> 4;
  int arow = node0 + col;
  float partial[4] = {0.f, 0.f, 0.f, 0.f};
  #pragma unroll
  for(int nt = 0; nt < 4; nt++){
    int o = nt * 16 + col;
    floatx4 acc = {0.f, 0.f, 0.f, 0.f};
    #pragma unroll
    for(int kc = 0; kc < 4; kc++){
      bf16x8 a = *(const bf16x8*)(h3 + arow * 128 + kc * 32 + quad * 8);
      bf16x8 b = *(const bf16x8*)(W4 + o * 192 + kc * 32 + quad * 8);
      acc = __builtin_amdgcn_mfma_f32_16x16x32_bf16(a, b, acc, 0, 0, 0);
    }
    #pragma unroll
    for(int kc = 0; kc < 2; kc++){
      bf16x8 a = *(const bf16x8*)(xb + arow * 64 + kc * 32 + quad * 8);
      bf16x8 b = *(const bf16x8*)(W4 + o * 192 + 128 + kc * 32 + quad * 8);
      acc = __builtin_amdgcn_mfma_f32_16x16x32_bf16(a, b, acc, 0, 0, 0);
    }
    float bb = b4[o];
    float w5 = W5[o];
    #pragma unroll
    for(int r = 0; r < 4; r++)
      partial[r] += fmaxf(acc[r] + bb, 0.f) * w5;
  }
  #pragma unroll
  for(int d = 1; d < 16; d <<= 1){
    #pragma unroll
    for(int r = 0; r < 4; r++)
      partial[r] += __shfl_xor(partial[r], d, 64);
  }
  if(col == 0){
    float b5f = b5[0];
    #pragma unroll
    for(int r = 0; r < 4; r++)
      out[node0 + quad * 4 + r] = partial[r] + b5f;
  }
}

extern "C" void kernel_launch(void* const* d_in, const int* in_sizes, int n_in,
                              void* d_out, int out_size, void* d_ws, size_t ws_size,
                              hipStream_t stream) {
  const float* x   = (const float*)d_in[0];
  const int* ei0   = (const int*)d_in[1];
  const int* ei1   = (const int*)d_in[2];
  const int* ei2   = (const int*)d_in[3];
  const float* ea  = (const float*)d_in[4];
  const float* W1  = (const float*)d_in[5];
  const float* b1  = (const float*)d_in[6];
  const float* g1  = (const float*)d_in[7];
  const float* be1 = (const float*)d_in[8];
  const float* m1  = (const float*)d_in[9];
  const float* v1  = (const float*)d_in[10];
  const float* Wl2 = (const float*)d_in[11];
  const float* bl2 = (const float*)d_in[12];
  const float* Wr2 = (const float*)d_in[13];
  const float* g2  = (const float*)d_in[14];
  const float* be2 = (const float*)d_in[15];
  const float* m2  = (const float*)d_in[16];
  const float* v2  = (const float*)d_in[17];
  const float* Wl3 = (const float*)d_in[18];
  const float* bl3 = (const float*)d_in[19];
  const float* Wr3 = (const float*)d_in[20];
  const float* g3  = (const float*)d_in[21];
  const float* be3 = (const float*)d_in[22];
  const float* m3  = (const float*)d_in[23];
  const float* v3  = (const float*)d_in[24];
  const float* W4  = (const float*)d_in[25];
  const float* b4  = (const float*)d_in[26];
  const float* W5  = (const float*)d_in[27];
  const float* b5  = (const float*)d_in[28];

  char* ws = (char*)d_ws;
  size_t off = 0;
  auto alloc = [&](size_t bytes) -> void* {
    void* p = (void*)(ws + off);
    off += (bytes + 255) & ~(size_t)255;
    return p;
  };
  int* gcur    = (int*)alloc(3 * KB * sizeof(int));
  int* rowbeg3 = (int*)alloc(3 * NN * sizeof(int));
  int* deg3    = (int*)alloc(3 * NN * sizeof(int));
  // UNION: phase 1 = rec (3 layers int2, 21.2MB); phase 2 = h1+h2 (25.6MB).
  char* uni    = (char*)alloc((size_t)2 * NN * 128 * 2);
  int2* adj2   = (int2*)alloc((size_t)KB * RCAP * 8);
  int* adjI1   = (int*)alloc((size_t)KB * RCAP * 4);
  int* adjI2   = (int*)alloc((size_t)KB * RCAP * 4);
  unsigned short* xb   = (unsigned short*)alloc((size_t)NN * 64 * 2);
  unsigned short* W1b  = (unsigned short*)alloc(12288 * 2);
  unsigned short* Wl2b = (unsigned short*)alloc(16384 * 2);
  unsigned short* Wr2b = (unsigned short*)alloc(16384 * 2);
  unsigned short* Wl3b = (unsigned short*)alloc(16384 * 2);
  unsigned short* Wr3b = (unsigned short*)alloc(16384 * 2);
  unsigned short* W4b  = (unsigned short*)alloc(12288 * 2);

  // phase-1 alias
  int2* recDS = (int2*)uni;
  // phase-2 aliases: h1 [0,12.8MB), h2 [12.8,25.6MB); h3 reuses h1's slot
  // (h1 dead after fused sage-L2: its last readers are that kernel's gathers/hin).
  unsigned short* h1   = (unsigned short*)uni;
  unsigned short* h2   = h1 + (size_t)NN * 128;
  unsigned short* h3   = h1;

  int* rb0 = rowbeg3;            int* dg0 = deg3;
  int* rb1 = rowbeg3 + NN;       int* dg1 = deg3 + NN;
  int* rb2 = rowbeg3 + 2 * NN;   int* dg2 = deg3 + 2 * NN;

  const int gP3   = 3 * NT2;                   // 1173
  const int gB3   = 3 * KB;                    // 588
  const int gFuse = NN / 16;                   // 3125 (x 1024 threads)
  const int gRead = (3125 * 64 + 255) / 256;   // 782
  const int gCvt  = (CVT_END + 255) / 256;

  k_cvt_all<<<gCvt, 256, 0, stream>>>(x, W1, Wl2, Wr2, Wl3, Wr3, W4,
                                      xb, W1b, Wl2b, Wr2b, Wl3b, Wr3b, W4b, gcur);

  // ---- fused partition + CSR build for all 3 layers ----
  k_part3<<<gP3, 256, 0, stream>>>(ei0, ei1, ei2, gcur, recDS);
  k_build3<<<gB3, 256, 0, stream>>>(recDS, gcur, ei0, adj2, adjI1, adjI2, rowbeg3, deg3);

  // ---- layer 1: fused gather + conv1 linear ----
  k_aggXElin<<<gFuse, 1024, 0, stream>>>(rb0, dg0, adj2, xb, ea,
                                         W1b, b1, g1, be1, m1, v1, h1);

  // ---- layer 2: fused gather + SAGE ----
  k_aggsage<<<gFuse, 1024, 0, stream>>>(rb1, dg1, adjI1, h1,
                                        Wl2b, bl2, Wr2b, g2, be2, m2, v2, h2);

  // ---- layer 3: fused gather + SAGE ----
  k_aggsage<<<gFuse, 1024, 0, stream>>>(rb2, dg2, adjI2, h2,
                                        Wl3b, bl3, Wr3b, g3, be3, m3, v3, h3);

  // ---- readout ----
  k_readout<<<gRead, 256, 0, stream>>>(h3, xb, W4b, b4, W5, b5, (float*)d_out);

  (void)in_sizes; (void)n_in; (void)out_size; (void)ws_size;
}